// Round 15
// baseline (161.949 us; speedup 1.0000x reference)
//
#include <hip/hip_runtime.h>

#define N_NODES 10000
#define N_EDGES 320000
#define EL (N_EDGES + N_NODES)
#define HC 256
#define CAP 96

using bf16x8 = __attribute__((ext_vector_type(8))) short;
using f32x4  = __attribute__((ext_vector_type(4))) float;

__device__ __forceinline__ float bf2f(unsigned short u) {
  union { unsigned int i; float f; } v; v.i = ((unsigned int)u) << 16; return v.f;
}
__device__ __forceinline__ unsigned short f2bf(float f) {
  union { float f; unsigned int i; } v; v.f = f;
  unsigned int r = (v.i + 0x7FFFu + ((v.i >> 16) & 1u)) >> 16;
  return (unsigned short)r;
}

// ---------------- prep: zero degree counters + transpose/convert 3 weight mats ----------

__device__ __forceinline__ void convw_body(const float* __restrict__ w,
                                           unsigned short* __restrict__ bt,
                                           int K, int idx) {
  int half = K >> 1;
  if (idx >= 256 * half) return;
  int col = idx / half;
  int k2 = (idx % half) * 2;
  ushort2 o;
  o.x = f2bf(w[(size_t)k2 * 256 + col]);
  o.y = f2bf(w[(size_t)(k2 + 1) * 256 + col]);
  *(ushort2*)(bt + (size_t)col * K + k2) = o;
}

__global__ __launch_bounds__(256) void prep_kernel(
    int* __restrict__ cnt,
    const float* __restrict__ w0, unsigned short* __restrict__ bt0,
    const float* __restrict__ w1, unsigned short* __restrict__ bt1,
    const float* __restrict__ w2, unsigned short* __restrict__ bt2) {
  int b = blockIdx.x, tid = threadIdx.x;
  if (b < 40) {
    int i = b * 256 + tid;
    if (i < N_NODES) cnt[i] = 0;
  } else if (b < 72) {
    convw_body(w0, bt0, 64, (b - 40) * 256 + tid);
  } else if (b < 200) {
    convw_body(w1, bt1, 256, (b - 72) * 256 + tid);
  } else {
    convw_body(w2, bt2, 256, (b - 200) * 256 + tid);
  }
}

// ---------------- scatter (buckets) + lin GEMM fused (independent work) ----------------

__global__ __launch_bounds__(256) void scatter_lin_kernel(
    const int* __restrict__ edges, int* __restrict__ cnt, int* __restrict__ slots,
    const float* __restrict__ A, const float* __restrict__ B,
    const float* __restrict__ bias, float* __restrict__ C) {
  int tid = threadIdx.x;
  if (blockIdx.x < 1290) {
    int e = blockIdx.x * 256 + tid;
    if (e >= EL) return;
    int s, d;
    if (e < N_EDGES) { s = edges[e]; d = edges[N_EDGES + e]; }
    else { s = d = e - N_EDGES; }
    int pos = atomicAdd(&cnt[d], 1);
    slots[d * CAP + pos] = s;
    return;
  }
  __shared__ float As[16][36];
  __shared__ float Bs[32][64];
  int row0 = (blockIdx.x - 1290) * 16;
  int g = tid >> 6, lane = tid & 63;
  float acc[4];
#pragma unroll
  for (int r = 0; r < 4; ++r) acc[r] = 0.f;
  for (int k0 = 0; k0 < 64; k0 += 32) {
    if (tid < 128) {
      int r = tid >> 3;
      int kc = (tid & 7) << 2;
      *(float4*)&As[r][kc] = *(const float4*)(A + (size_t)(row0 + r) * 64 + k0 + kc);
    }
    {
#pragma unroll
      for (int i = 0; i < 2; ++i) {
        int fidx = (i * 256 + tid) * 4;
        int kk = fidx >> 6;
        int cc = fidx & 63;
        *(float4*)&Bs[kk][cc] = *(const float4*)(B + (size_t)(k0 + kk) * 64 + cc);
      }
    }
    __syncthreads();
#pragma unroll
    for (int kk = 0; kk < 32; kk += 4) {
      float a4[4][4];
#pragma unroll
      for (int rr = 0; rr < 4; ++rr) {
        float4 t = *(const float4*)&As[g * 4 + rr][kk];
        a4[rr][0] = t.x; a4[rr][1] = t.y; a4[rr][2] = t.z; a4[rr][3] = t.w;
      }
#pragma unroll
      for (int u = 0; u < 4; ++u) {
        float b = Bs[kk + u][lane];
#pragma unroll
        for (int rr = 0; rr < 4; ++rr) acc[rr] = fmaf(a4[rr][u], b, acc[rr]);
      }
    }
    __syncthreads();
  }
#pragma unroll
  for (int rr = 0; rr < 4; ++rr) {
    int row = row0 + g * 4 + rr;
    C[(size_t)row * 64 + lane] = fmaxf(acc[rr] + bias[lane], 0.f);
  }
}

// ---------------- MFMA GEMM (attn layers): Cb[M][256] bf16 = A[M][K] @ W, + attn dots ----

template <int K>
__global__ __launch_bounds__(256) void gemm_attn_mfma(
    const float* __restrict__ A, const unsigned short* __restrict__ Bt,
    unsigned short* __restrict__ Cb,
    const float* __restrict__ att_src, const float* __restrict__ att_dst,
    float* __restrict__ asrc_out, float* __restrict__ adst_out) {
  __shared__ __align__(16) unsigned short Asw[16 * 64];
  __shared__ __align__(16) unsigned short Bsw[256 * 64];
  int tid = threadIdx.x;
  int wave = tid >> 6, lane = tid & 63;
  int r = lane & 15, g = lane >> 4;
  int row0 = blockIdx.x * 16;

  f32x4 acc[4];
#pragma unroll
  for (int i = 0; i < 4; ++i) acc[i] = {0.f, 0.f, 0.f, 0.f};

  for (int k0 = 0; k0 < K; k0 += 64) {
    {
      int ar = tid >> 4;
      int kc = (tid & 15) << 2;
      float4 av = *(const float4*)(A + (size_t)(row0 + ar) * K + k0 + kc);
      ushort4 o;
      o.x = f2bf(av.x); o.y = f2bf(av.y); o.z = f2bf(av.z); o.w = f2bf(av.w);
      *(ushort4*)((char*)Asw + ((ar * 128 + kc * 2) ^ ((ar & 7) << 4))) = o;
    }
#pragma unroll
    for (int i = 0; i < 8; ++i) {
      int idx = i * 256 + tid;
      int col = idx >> 3;
      int kc8 = idx & 7;
      uint4 v = *(const uint4*)(Bt + (size_t)col * K + k0 + kc8 * 8);
      *(uint4*)((char*)Bsw + ((col * 128 + kc8 * 16) ^ ((col & 7) << 4))) = v;
    }
    __syncthreads();
#pragma unroll
    for (int chunk = 0; chunk < 2; ++chunk) {
      bf16x8 af = *(const bf16x8*)((char*)Asw +
                    ((r * 128 + chunk * 64 + g * 16) ^ ((r & 7) << 4)));
#pragma unroll
      for (int i = 0; i < 4; ++i) {
        int col = (wave * 4 + i) * 16 + r;
        bf16x8 bfr = *(const bf16x8*)((char*)Bsw +
                       ((col * 128 + chunk * 64 + g * 16) ^ ((col & 7) << 4)));
        acc[i] = __builtin_amdgcn_mfma_f32_16x16x32_bf16(af, bfr, acc[i], 0, 0, 0);
      }
    }
    __syncthreads();
  }

  float asv[4], adv[4];
#pragma unroll
  for (int i = 0; i < 4; ++i) {
    int col = (wave * 4 + i) * 16 + r;
    asv[i] = att_src[col];
    adv[i] = att_dst[col];
  }
#pragma unroll
  for (int j = 0; j < 4; ++j) {
    float ps = acc[0][j] * asv[0] + acc[1][j] * asv[1] + acc[2][j] * asv[2] + acc[3][j] * asv[3];
    float pd = acc[0][j] * adv[0] + acc[1][j] * adv[1] + acc[2][j] * adv[2] + acc[3][j] * adv[3];
#pragma unroll
    for (int m = 8; m >= 1; m >>= 1) {
      ps += __shfl_xor(ps, m);
      pd += __shfl_xor(pd, m);
    }
    if (r == 0) {
      int row = row0 + g * 4 + j;
      asrc_out[row * 4 + wave] = ps;
      adst_out[row * 4 + wave] = pd;
    }
  }

#pragma unroll
  for (int i = 0; i < 4; ++i) {
    int col = (wave * 4 + i) * 16 + r;
#pragma unroll
    for (int j = 0; j < 4; ++j) {
      int row = row0 + g * 4 + j;
      Cb[(size_t)row * 256 + col] = f2bf(acc[i][j]);
    }
  }
}

// ---------------- fused GAT aggregation + bias + ELU + residual + LayerNorm ----------------
// Half-wave edge parallelism + chunk-8 pipeline (8 outstanding 16B gathers/lane).
// Lanes 0-31: first half of edge list; lanes 32-63: second half; 8 channels/lane.
// Combine via shfl_xor(32); epilogue ownership cb = (lane&31)*8 + (lane>>5)*4.

template <int MODE>
__global__ __launch_bounds__(256) void agg_kernel(
    const int* __restrict__ cnt, const int* __restrict__ slots,
    const float* __restrict__ asrc, const float* __restrict__ adst,
    const unsigned short* __restrict__ xb, const float* __restrict__ bias,
    const float* __restrict__ resid, const float* __restrict__ ln_g,
    const float* __restrict__ ln_b, float* __restrict__ hout) {
  int w = threadIdx.x >> 6, lane = threadIdx.x & 63;
  int n = blockIdx.x * 4 + w;
  int lh = lane & 31;
  int half = lane >> 5;
  int h = lh >> 3;
  int ch8 = lh << 3;
  float ad = adst[n * 4 + h];

  int i0 = n * CAP;
  int deg = cnt[n];
  int len0 = (deg + 1) >> 1;
  int beg = i0 + (half ? len0 : 0);
  int end = i0 + (half ? deg : len0);
  int last = end - 1;  // deg>=1 (self-loop) so last>=i0 even if this half is empty

  float a0 = 0.f, a1 = 0.f, a2 = 0.f, a3 = 0.f, a4 = 0.f, a5 = 0.f, a6 = 0.f, a7 = 0.f;
  float wsum = 0.f;

  int sA[8];
#pragma unroll
  for (int j = 0; j < 8; ++j) sA[j] = slots[min(beg + j, last)];
  float ca[8]; uint4 cx[8];
#pragma unroll
  for (int j = 0; j < 8; ++j) {
    ca[j] = asrc[sA[j] * 4 + h];
    cx[j] = *(const uint4*)(xb + (size_t)sA[j] * HC + ch8);
  }
#pragma unroll
  for (int j = 0; j < 8; ++j) sA[j] = slots[min(beg + 8 + j, last)];

  for (int base = beg; base < end; base += 8) {
    float na[8]; uint4 nx[8];
#pragma unroll
    for (int j = 0; j < 8; ++j) {
      na[j] = asrc[sA[j] * 4 + h];
      nx[j] = *(const uint4*)(xb + (size_t)sA[j] * HC + ch8);
    }
#pragma unroll
    for (int j = 0; j < 8; ++j) sA[j] = slots[min(base + 16 + j, last)];
#pragma unroll
    for (int j = 0; j < 8; ++j) {
      float e = ca[j] + ad;
      e = e > 0.f ? e : 0.2f * e;
      float wg = __expf(e);
      wg = (base + j < end) ? wg : 0.f;
      wsum += wg;
      a0 = fmaf(wg, bf2f((unsigned short)(cx[j].x & 0xffff)), a0);
      a1 = fmaf(wg, bf2f((unsigned short)(cx[j].x >> 16)), a1);
      a2 = fmaf(wg, bf2f((unsigned short)(cx[j].y & 0xffff)), a2);
      a3 = fmaf(wg, bf2f((unsigned short)(cx[j].y >> 16)), a3);
      a4 = fmaf(wg, bf2f((unsigned short)(cx[j].z & 0xffff)), a4);
      a5 = fmaf(wg, bf2f((unsigned short)(cx[j].z >> 16)), a5);
      a6 = fmaf(wg, bf2f((unsigned short)(cx[j].w & 0xffff)), a6);
      a7 = fmaf(wg, bf2f((unsigned short)(cx[j].w >> 16)), a7);
    }
#pragma unroll
    for (int j = 0; j < 8; ++j) { ca[j] = na[j]; cx[j] = nx[j]; }
  }

  // combine halves
  a0 += __shfl_xor(a0, 32); a1 += __shfl_xor(a1, 32);
  a2 += __shfl_xor(a2, 32); a3 += __shfl_xor(a3, 32);
  a4 += __shfl_xor(a4, 32); a5 += __shfl_xor(a5, 32);
  a6 += __shfl_xor(a6, 32); a7 += __shfl_xor(a7, 32);
  wsum += __shfl_xor(wsum, 32);

  int cb = ch8 + half * 4;
  float v0 = half ? a4 : a0;
  float v1 = half ? a5 : a1;
  float v2 = half ? a6 : a2;
  float v3 = half ? a7 : a3;

  float rw = 1.f / wsum;
  float4 b4 = *(const float4*)(bias + cb);
  v0 = fmaf(v0, rw, b4.x);
  v1 = fmaf(v1, rw, b4.y);
  v2 = fmaf(v2, rw, b4.z);
  v3 = fmaf(v3, rw, b4.w);
  v0 = v0 > 0.f ? v0 : __expf(v0) - 1.f;
  v1 = v1 > 0.f ? v1 : __expf(v1) - 1.f;
  v2 = v2 > 0.f ? v2 : __expf(v2) - 1.f;
  v3 = v3 > 0.f ? v3 : __expf(v3) - 1.f;

  if constexpr (MODE == 0) {
    if (cb < 64) {
      float4 r = *(const float4*)(resid + (size_t)n * 64 + cb);
      v0 += r.x; v1 += r.y; v2 += r.z; v3 += r.w;
    }
  } else {
    float4 r = *(const float4*)(resid + (size_t)n * HC + cb);
    v0 += r.x; v1 += r.y; v2 += r.z; v3 += r.w;
  }

  float s1 = v0 + v1 + v2 + v3;
  float s2 = v0 * v0 + v1 * v1 + v2 * v2 + v3 * v3;
#pragma unroll
  for (int m = 32; m >= 1; m >>= 1) {
    s1 += __shfl_xor(s1, m);
    s2 += __shfl_xor(s2, m);
  }
  float mean = s1 * (1.f / 256.f);
  float var = s2 * (1.f / 256.f) - mean * mean;
  float inv = rsqrtf(var + 1e-5f);

  float4 g4 = *(const float4*)(ln_g + cb);
  float4 lb4 = *(const float4*)(ln_b + cb);
  float4 o;
  o.x = (v0 - mean) * inv * g4.x + lb4.x;
  o.y = (v1 - mean) * inv * g4.y + lb4.y;
  o.z = (v2 - mean) * inv * g4.z + lb4.z;
  o.w = (v3 - mean) * inv * g4.w + lb4.w;
  *(float4*)(hout + (size_t)n * HC + cb) = o;
}

// ---------------- fused FFN: out = relu(hA@w1+b1)@w2 + b2, mid kept in LDS -------------

__global__ __launch_bounds__(256) void ffn_kernel(const float* __restrict__ A,
                                                  const float* __restrict__ w1,
                                                  const float* __restrict__ b1,
                                                  const float* __restrict__ w2,
                                                  const float* __restrict__ b2,
                                                  float* __restrict__ out) {
  __shared__ float As[16][36];
  __shared__ float Bs[32][128];
  __shared__ float Ms[16][132];
  int tid = threadIdx.x;
  int row0 = blockIdx.x * 16;
  int g = tid >> 6, lane = tid & 63;

  {
    int colBase = lane * 2;
    float acc[4][2];
#pragma unroll
    for (int r = 0; r < 4; ++r) { acc[r][0] = 0.f; acc[r][1] = 0.f; }
    for (int k0 = 0; k0 < 256; k0 += 32) {
      if (tid < 128) {
        int r = tid >> 3;
        int kc = (tid & 7) << 2;
        *(float4*)&As[r][kc] = *(const float4*)(A + (size_t)(row0 + r) * 256 + k0 + kc);
      }
#pragma unroll
      for (int i = 0; i < 4; ++i) {
        int fidx = (i * 256 + tid) * 4;
        int kk = fidx >> 7;
        int cc = fidx & 127;
        *(float4*)&Bs[kk][cc] = *(const float4*)(w1 + (size_t)(k0 + kk) * 128 + cc);
      }
      __syncthreads();
#pragma unroll
      for (int kk = 0; kk < 32; kk += 4) {
        float a4[4][4];
#pragma unroll
        for (int rr = 0; rr < 4; ++rr) {
          float4 t = *(const float4*)&As[g * 4 + rr][kk];
          a4[rr][0] = t.x; a4[rr][1] = t.y; a4[rr][2] = t.z; a4[rr][3] = t.w;
        }
#pragma unroll
        for (int u = 0; u < 4; ++u) {
          float2 b = *(const float2*)&Bs[kk + u][colBase];
#pragma unroll
          for (int rr = 0; rr < 4; ++rr) {
            acc[rr][0] = fmaf(a4[rr][u], b.x, acc[rr][0]);
            acc[rr][1] = fmaf(a4[rr][u], b.y, acc[rr][1]);
          }
        }
      }
      __syncthreads();
    }
    float bb0 = b1[colBase], bb1 = b1[colBase + 1];
#pragma unroll
    for (int rr = 0; rr < 4; ++rr) {
      Ms[g * 4 + rr][colBase]     = fmaxf(acc[rr][0] + bb0, 0.f);
      Ms[g * 4 + rr][colBase + 1] = fmaxf(acc[rr][1] + bb1, 0.f);
    }
  }
  __syncthreads();

  {
    float acc[4];
#pragma unroll
    for (int r = 0; r < 4; ++r) acc[r] = 0.f;
    for (int k0 = 0; k0 < 128; k0 += 32) {
#pragma unroll
      for (int i = 0; i < 2; ++i) {
        int fidx = (i * 256 + tid) * 4;
        int kk = fidx >> 6;
        int cc = fidx & 63;
        *(float4*)&Bs[kk][cc] = *(const float4*)(w2 + (size_t)(k0 + kk) * 64 + cc);
      }
      __syncthreads();
#pragma unroll
      for (int kk = 0; kk < 32; ++kk) {
        float b = Bs[kk][lane];
#pragma unroll
        for (int rr = 0; rr < 4; ++rr)
          acc[rr] = fmaf(Ms[g * 4 + rr][k0 + kk], b, acc[rr]);
      }
      __syncthreads();
    }
    float bb = b2[lane];
#pragma unroll
    for (int rr = 0; rr < 4; ++rr) {
      int row = row0 + g * 4 + rr;
      out[(size_t)row * 64 + lane] = acc[rr] + bb;
    }
  }
}

// ---------------- launch ----------------

extern "C" void kernel_launch(void* const* d_in, const int* in_sizes, int n_in,
                              void* d_out, int out_size, void* d_ws, size_t ws_size,
                              hipStream_t stream) {
  (void)in_sizes; (void)n_in; (void)out_size; (void)ws_size;
  const float* x      = (const float*)d_in[0];
  const int*   edges  = (const int*)d_in[1];
  const float* lin_w  = (const float*)d_in[2];
  const float* lin_b  = (const float*)d_in[3];
  const float* gat_w[3] = {(const float*)d_in[4], (const float*)d_in[10], (const float*)d_in[16]};
  const float* att_s[3] = {(const float*)d_in[5], (const float*)d_in[11], (const float*)d_in[17]};
  const float* att_d[3] = {(const float*)d_in[6], (const float*)d_in[12], (const float*)d_in[18]};
  const float* gat_b[3] = {(const float*)d_in[7], (const float*)d_in[13], (const float*)d_in[19]};
  const float* ln_g[3]  = {(const float*)d_in[8], (const float*)d_in[14], (const float*)d_in[20]};
  const float* ln_b[3]  = {(const float*)d_in[9], (const float*)d_in[15], (const float*)d_in[21]};
  const float* ffn_w1 = (const float*)d_in[22];
  const float* ffn_b1 = (const float*)d_in[23];
  const float* ffn_w2 = (const float*)d_in[24];
  const float* ffn_b2 = (const float*)d_in[25];

  char* p = (char*)d_ws;
  auto alloc = [&](size_t bytes) {
    char* q = p;
    p += (bytes + 255) & ~(size_t)255;
    return q;
  };
  int* cnt   = (int*)alloc(N_NODES * 4);
  int* slots = (int*)alloc((size_t)N_NODES * CAP * 4);
  float* h0  = (float*)alloc((size_t)N_NODES * 64 * 4);
  float* hA  = (float*)alloc((size_t)N_NODES * HC * 4);
  float* hB  = (float*)alloc((size_t)N_NODES * HC * 4);
  unsigned short* xb = (unsigned short*)alloc((size_t)N_NODES * HC * 2);
  float* as4 = (float*)alloc((size_t)N_NODES * 16);
  float* ad4 = (float*)alloc((size_t)N_NODES * 16);
  unsigned short* bt0 = (unsigned short*)alloc(256 * 64 * 2);
  unsigned short* bt1 = (unsigned short*)alloc(256 * 256 * 2);
  unsigned short* bt2 = (unsigned short*)alloc(256 * 256 * 2);

  const int gblk = N_NODES / 16;      // 625
  const int nblk = N_NODES / 4;       // 2500

  prep_kernel<<<328, 256, 0, stream>>>(cnt, gat_w[0], bt0, gat_w[1], bt1, gat_w[2], bt2);
  scatter_lin_kernel<<<1290 + 625, 256, 0, stream>>>(edges, cnt, slots, x, lin_w, lin_b, h0);

  // layer 0
  gemm_attn_mfma<64><<<gblk, 256, 0, stream>>>(h0, bt0, xb, att_s[0], att_d[0], as4, ad4);
  agg_kernel<0><<<nblk, 256, 0, stream>>>(cnt, slots, as4, ad4, xb, gat_b[0], h0,
                                          ln_g[0], ln_b[0], hA);
  // layer 1
  gemm_attn_mfma<256><<<gblk, 256, 0, stream>>>(hA, bt1, xb, att_s[1], att_d[1], as4, ad4);
  agg_kernel<1><<<nblk, 256, 0, stream>>>(cnt, slots, as4, ad4, xb, gat_b[1], hA,
                                          ln_g[1], ln_b[1], hB);
  // layer 2
  gemm_attn_mfma<256><<<gblk, 256, 0, stream>>>(hB, bt2, xb, att_s[2], att_d[2], as4, ad4);
  agg_kernel<1><<<nblk, 256, 0, stream>>>(cnt, slots, as4, ad4, xb, gat_b[2], hB,
                                          ln_g[2], ln_b[2], hA);

  // fused FFN
  ffn_kernel<<<gblk, 256, 0, stream>>>(hA, ffn_w1, ffn_b1, ffn_w2, ffn_b2, (float*)d_out);
}